// Round 4
// baseline (289.087 us; speedup 1.0000x reference)
//
#include <hip/hip_runtime.h>
#include <stdint.h>

#define LOG2E 1.44269504088896340736f

typedef __bf16 v8bf __attribute__((ext_vector_type(8)));
typedef float f32x4 __attribute__((ext_vector_type(4)));
typedef unsigned int v4u __attribute__((ext_vector_type(4)));

// ---------- helpers ----------
__device__ __forceinline__ unsigned short f2bf(float f) {
  union { float f; uint32_t u; } v; v.f = f;
  uint32_t u = v.u;
  uint32_t r = (u + 0x7FFFu + ((u >> 16) & 1u)) >> 16;   // RN-even
  return (unsigned short)r;
}
__device__ __forceinline__ float bf2f(unsigned short h) {
  union { uint32_t u; float f; } v; v.u = ((uint32_t)h) << 16;
  return v.f;
}
__device__ __forceinline__ void gll16(const void* g, void* l) {
  __builtin_amdgcn_global_load_lds(
      (const __attribute__((address_space(1))) unsigned int*)g,
      (__attribute__((address_space(3))) unsigned int*)l, 16, 0, 0);
}

// ---------- prep: x -> [hi | lo | hi]  (4096 x 2304 bf16) ----------
__global__ void prep_a(const float* __restrict__ x, unsigned short* __restrict__ Acat) {
  int n = blockIdx.x * 256 + threadIdx.x;   // 0..767
  int m = blockIdx.y;                       // 0..4095
  float v = x[(size_t)m * 768 + n];
  unsigned short H = f2bf(v);
  unsigned short L = f2bf(v - bf2f(H));
  size_t base = (size_t)m * 2304;
  Acat[base + n] = H;
  Acat[base + 768 + n] = L;
  Acat[base + 1536 + n] = H;
}

// ---------- prep: Wqkv^T cat -> rows n: [Whi | Whi | Wlo] (2304 x 2304 bf16) ----------
__global__ void prep_bqkv(const float* __restrict__ W, unsigned short* __restrict__ BT) {
  int k = blockIdx.x * 256 + threadIdx.x;   // 0..767
  int n = blockIdx.y;                       // 0..2303
  float v = W[(size_t)k * 2304 + n];
  unsigned short H = f2bf(v);
  unsigned short L = f2bf(v - bf2f(H));
  size_t base = (size_t)n * 2304;
  BT[base + k] = H;
  BT[base + 768 + k] = H;
  BT[base + 1536 + k] = L;
}

// ---------- prep: Wout^T single bf16 (768 x 768) ----------
__global__ void prep_wout(const float* __restrict__ W, unsigned short* __restrict__ BT) {
  int k = blockIdx.x * 256 + threadIdx.x;   // 0..767
  int n = blockIdx.y;                       // 0..767
  BT[(size_t)n * 768 + k] = f2bf(W[(size_t)k * 768 + n]);
}

// ---------- GEMM: C[M,N] = A[M,K](bf16) * B^T[N,K](bf16) + bias[N], fp32 out ----------
__global__ __launch_bounds__(256) void gemm_bf16_128(
    const unsigned short* __restrict__ A, const unsigned short* __restrict__ B,
    const float* __restrict__ bias, float* __restrict__ C,
    int M, int N, int K) {
  __shared__ unsigned short As[128 * 32];
  __shared__ unsigned short Bs[128 * 32];
  const int t = threadIdx.x;
  const int m0 = blockIdx.y * 128, n0 = blockIdx.x * 128;
  const int w = t >> 6, l = t & 63;
  const int wm = (w >> 1) * 64, wn = (w & 1) * 64;
  const int lr = l & 15, lg = l >> 4;
  f32x4 acc[4][4] = {};
  const int nk = K >> 5;
  for (int kt = 0; kt < nk; ++kt) {
    const int k0 = kt << 5;
    {
      const int c0 = t, c1 = t + 256;
      gll16(A + (size_t)(m0 + (c0 >> 2)) * K + k0 + ((c0 & 3) << 3), &As[c0 * 8]);
      gll16(A + (size_t)(m0 + (c1 >> 2)) * K + k0 + ((c1 & 3) << 3), &As[c1 * 8]);
      gll16(B + (size_t)(n0 + (c0 >> 2)) * K + k0 + ((c0 & 3) << 3), &Bs[c0 * 8]);
      gll16(B + (size_t)(n0 + (c1 >> 2)) * K + k0 + ((c1 & 3) << 3), &Bs[c1 * 8]);
    }
    __syncthreads();
    v8bf a[4], b[4];
#pragma unroll
    for (int i = 0; i < 4; i++) {
      a[i] = *(const v8bf*)&As[(wm + i * 16 + lr) * 32 + lg * 8];
      b[i] = *(const v8bf*)&Bs[(wn + i * 16 + lr) * 32 + lg * 8];
    }
#pragma unroll
    for (int i = 0; i < 4; i++)
#pragma unroll
      for (int j = 0; j < 4; j++)
        acc[i][j] = __builtin_amdgcn_mfma_f32_16x16x32_bf16(a[i], b[j], acc[i][j], 0, 0, 0);
    __syncthreads();
  }
#pragma unroll
  for (int i = 0; i < 4; i++) {
#pragma unroll
    for (int j = 0; j < 4; j++) {
      const int col = n0 + wn + j * 16 + lr;
      const float bv = bias[col];
#pragma unroll
      for (int r = 0; r < 4; r++) {
        const int row = m0 + wm + i * 16 + lg * 4 + r;
        C[(size_t)row * N + col] = acc[i][j][r] + bv;
      }
    }
  }
}

// ---------- split qkv fp32 -> Qcat/Kcat (split-bf16, *8 folded into Q), V^T bf16 ----------
__global__ void split_qkv(const float* __restrict__ qkv,
                          unsigned short* __restrict__ Qc,
                          unsigned short* __restrict__ Kc,
                          unsigned short* __restrict__ VT) {
  int n = blockIdx.x * 256 + threadIdx.x;   // 0..2303
  int m = blockIdx.y;                       // 0..4095
  float val = qkv[(size_t)m * 2304 + n];
  int h = n / 192;
  int j = n - h * 192;
  int b = m >> 11, p = m & 2047;
  int bh = b * 12 + h;
  size_t base = (size_t)bh * 2048 * 192 + (size_t)p * 192;
  if (j < 64) {
    float v8v = val * 8.0f;                 // fold logits *= sqrt(64) (exact: pow2)
    unsigned short H = f2bf(v8v);
    unsigned short L = f2bf(v8v - bf2f(H));
    Qc[base + j] = H; Qc[base + 64 + j] = L; Qc[base + 128 + j] = H;
  } else if (j < 128) {
    int d = j - 64;
    unsigned short H = f2bf(val);
    unsigned short L = f2bf(val - bf2f(H));
    Kc[base + d] = H; Kc[base + 64 + d] = H; Kc[base + 128 + d] = L;
  } else {
    int d = j - 128;
    VT[(size_t)bh * 64 * 2048 + (size_t)d * 2048 + p] = f2bf(val);
  }
}

// ---------- flash attention, split-K x2 ----------
// grid (32 q-tiles, 24 bh, 2 key-splits), 256 threads = 4 waves.
// Each split handles 16 K-tiles (1024 keys), emits unnormalized partial O (f32)
// + per-row (m, l) to workspace; attn_combine merges the two splits.
// T14 async-STAGE (reg-staged K/V, issue-early/write-late), LDS XOR-swizzle
// (write+read both ^ (row&7)<<3), T13 defer-max (THR=8), T5 setprio on MFMA.
__global__ __launch_bounds__(256) void attn(
    const unsigned short* __restrict__ Qc, const unsigned short* __restrict__ Kc,
    const unsigned short* __restrict__ VT,
    float* __restrict__ Op, float* __restrict__ Ml) {
  __shared__ __align__(16) unsigned short Ks[64 * 192];
  __shared__ __align__(16) unsigned short Vs[64 * 64];
  __shared__ __align__(16) __bf16 Ps[4][16 * 64];
  const int t = threadIdx.x, w = t >> 6, l = t & 63, lr = l & 15, lg = l >> 4;
  const int bh = blockIdx.y, q0 = blockIdx.x * 64;
  const int ktBase = blockIdx.z * 16;           // 16 K-tiles per split
  const unsigned short* Qb = Qc + (size_t)bh * 2048 * 192;
  const unsigned short* Kb = Kc + (size_t)bh * 2048 * 192;
  const unsigned short* Vb = VT + (size_t)bh * 64 * 2048;

  // hoisted swizzled LDS write offsets (element units)
  int kwofs[6];
#pragma unroll
  for (int i = 0; i < 6; i++) {
    int c = t + i * 256;                    // 16B chunk id; 24 chunks per 192-elem row
    int row = c / 24, cc = c - row * 24;
    kwofs[i] = (row * 192 + cc * 8) ^ ((row & 7) << 3);
  }
  int vwofs[2];
#pragma unroll
  for (int i = 0; i < 2; i++) {
    int c = t + i * 256;                    // 8 chunks per 64-elem V^T row
    int d = c >> 3, part = c & 7;
    vwofs[i] = (d * 64 + part * 8) ^ ((d & 7) << 3);
  }
  // linear global source pointers (coalesced), bumped per kt
  const char* gK = (const char*)Kb + (size_t)ktBase * 24576 + (size_t)t * 16;
  const char* gV = (const char*)Vb + (size_t)(t >> 3) * 4096 + (size_t)(t & 7) * 16
                   + (size_t)ktBase * 128;

  v4u kreg[6], vreg[2];
#pragma unroll
  for (int i = 0; i < 6; i++) kreg[i] = *(const v4u*)(gK + i * 4096);
#pragma unroll
  for (int i = 0; i < 2; i++) vreg[i] = *(const v4u*)(gV + i * 131072);

  v8bf qf[6];
  const int qrow = q0 + w * 16 + lr;
#pragma unroll
  for (int ks = 0; ks < 6; ++ks)
    qf[ks] = *(const v8bf*)(Qb + (size_t)qrow * 192 + ks * 32 + lg * 8);

  f32x4 o[4] = {};
  float mrow[4], lrow[4];
#pragma unroll
  for (int j = 0; j < 4; j++) { mrow[j] = -1e30f; lrow[j] = 0.f; }

  const int sx = (lr & 7) << 3;   // read-side swizzle for rows == (16k + lr)

  for (int kt = 0; kt < 16; ++kt) {
    // drain staged regs to LDS (compiler inserts vmcnt waits on first use)
#pragma unroll
    for (int i = 0; i < 6; i++) *(v4u*)&Ks[kwofs[i]] = kreg[i];
#pragma unroll
    for (int i = 0; i < 2; i++) *(v4u*)&Vs[vwofs[i]] = vreg[i];
    __syncthreads();

    // issue next tile's loads — in flight during this tile's compute
    if (kt < 15) {
      gK += 24576; gV += 128;
#pragma unroll
      for (int i = 0; i < 6; i++) kreg[i] = *(const v4u*)(gK + i * 4096);
#pragma unroll
      for (int i = 0; i < 2; i++) vreg[i] = *(const v4u*)(gV + i * 131072);
    }

    // S = Q K^T (scale pre-folded into Q)
    f32x4 s[4] = {};
    __builtin_amdgcn_s_setprio(1);
#pragma unroll
    for (int nf = 0; nf < 4; nf++) {
#pragma unroll
      for (int ks = 0; ks < 6; ks++) {
        v8bf bfrag = *(const v8bf*)&Ks[(((nf * 16 + lr) * 192) + ks * 32 + lg * 8) ^ sx];
        s[nf] = __builtin_amdgcn_mfma_f32_16x16x32_bf16(qf[ks], bfrag, s[nf], 0, 0, 0);
      }
    }
    __builtin_amdgcn_s_setprio(0);

    // online softmax with defer-max (THR=8): keep stale m while tile max
    // doesn't exceed it by >8; P bounded by e^8 (fine in bf16/f32).
    float pmax[4];
#pragma unroll
    for (int j = 0; j < 4; j++) {
      float mv = fmaxf(fmaxf(s[0][j], s[1][j]), fmaxf(s[2][j], s[3][j]));
      mv = fmaxf(mv, __shfl_xor(mv, 1));
      mv = fmaxf(mv, __shfl_xor(mv, 2));
      mv = fmaxf(mv, __shfl_xor(mv, 4));
      mv = fmaxf(mv, __shfl_xor(mv, 8));
      pmax[j] = mv;
    }
    bool defer = pmax[0] <= mrow[0] + 8.f && pmax[1] <= mrow[1] + 8.f &&
                 pmax[2] <= mrow[2] + 8.f && pmax[3] <= mrow[3] + 8.f;
    if (!__all(defer ? 1 : 0)) {
#pragma unroll
      for (int j = 0; j < 4; j++) {
        float mnew = fmaxf(mrow[j], pmax[j]);
        float a = __builtin_exp2f((mrow[j] - mnew) * LOG2E);
        mrow[j] = mnew;
        lrow[j] *= a;
        o[0][j] *= a; o[1][j] *= a; o[2][j] *= a; o[3][j] *= a;
      }
    }
    float psum[4] = {0.f, 0.f, 0.f, 0.f};
    __bf16 pb[4][4];
#pragma unroll
    for (int nf = 0; nf < 4; nf++) {
#pragma unroll
      for (int j = 0; j < 4; j++) {
        float p = __builtin_exp2f((s[nf][j] - mrow[j]) * LOG2E);
        psum[j] += p;
        pb[nf][j] = (__bf16)p;
      }
    }
#pragma unroll
    for (int j = 0; j < 4; j++) {
      float ps = psum[j];
      ps += __shfl_xor(ps, 1);
      ps += __shfl_xor(ps, 2);
      ps += __shfl_xor(ps, 4);
      ps += __shfl_xor(ps, 8);
      lrow[j] += ps;
    }

    // P -> LDS (re-layout C-frag -> A-frag), swizzled store
#pragma unroll
    for (int nf = 0; nf < 4; nf++)
#pragma unroll
      for (int j = 0; j < 4; j++) {
        int row = lg * 4 + j;
        Ps[w][((row * 64) + nf * 16 + lr) ^ ((row & 7) << 3)] = pb[nf][j];
      }

    // O += P V   (B-operand rows are V^T rows), swizzled reads
    v8bf pa[2];
#pragma unroll
    for (int ks = 0; ks < 2; ks++)
      pa[ks] = *(const v8bf*)&Ps[w][((lr * 64) + ks * 32 + lg * 8) ^ sx];
    __builtin_amdgcn_s_setprio(1);
#pragma unroll
    for (int df = 0; df < 4; df++) {
#pragma unroll
      for (int ks = 0; ks < 2; ks++) {
        v8bf vb2 = *(const v8bf*)&Vs[(((df * 16 + lr) * 64) + ks * 32 + lg * 8) ^ sx];
        o[df] = __builtin_amdgcn_mfma_f32_16x16x32_bf16(pa[ks], vb2, o[df], 0, 0, 0);
      }
    }
    __builtin_amdgcn_s_setprio(0);
    __syncthreads();
  }

  // epilogue: partial (unnormalized) O + (m,l) per row
  const size_t S = (size_t)24 * 2048;
  const size_t srow = (size_t)blockIdx.z * S + (size_t)bh * 2048;
#pragma unroll
  for (int j = 0; j < 4; j++) {
    const int q = q0 + w * 16 + lg * 4 + j;
    const size_t rbase = (srow + q) * 64;
#pragma unroll
    for (int df = 0; df < 4; df++)
      Op[rbase + df * 16 + lr] = o[df][j];
    if (lr == 0) {
      Ml[(srow + q) * 2]     = mrow[j];
      Ml[(srow + q) * 2 + 1] = lrow[j];
    }
  }
}

// ---------- combine the two split-K partials ----------
__global__ __launch_bounds__(256) void attn_combine(
    const float* __restrict__ Op, const float* __restrict__ Ml,
    __bf16* __restrict__ Oe) {
  const size_t S = (size_t)24 * 2048;
  int row = blockIdx.x * 4 + (threadIdx.x >> 6);   // bh*2048 + q, 0..49151
  int lane = threadIdx.x & 63;
  int bh = row >> 11, q = row & 2047;
  int b = bh / 12, h = bh - b * 12;
  float m1 = Ml[(size_t)row * 2], l1 = Ml[(size_t)row * 2 + 1];
  float m2 = Ml[(S + row) * 2],   l2 = Ml[(S + row) * 2 + 1];
  float M = fmaxf(m1, m2);
  float a1 = __builtin_exp2f((m1 - M) * LOG2E);
  float a2 = __builtin_exp2f((m2 - M) * LOG2E);
  float rinv = 1.0f / (l1 * a1 + l2 * a2);
  float o1 = Op[(size_t)row * 64 + lane];
  float o2 = Op[S * 64 + (size_t)row * 64 + lane];
  Oe[((size_t)(b * 2048 + q)) * 768 + h * 64 + lane] = (__bf16)((o1 * a1 + o2 * a2) * rinv);
}

// ---------- launcher ----------
extern "C" void kernel_launch(void* const* d_in, const int* in_sizes, int n_in,
                              void* d_out, int out_size, void* d_ws, size_t ws_size,
                              hipStream_t stream) {
  const float* x    = (const float*)d_in[0];
  const float* Wqkv = (const float*)d_in[1];
  const float* bqkv = (const float*)d_in[2];
  const float* Wout = (const float*)d_in[3];
  const float* bout = (const float*)d_in[4];
  float* out = (float*)d_out;
  char* ws = (char*)d_ws;

  unsigned short* Acat  = (unsigned short*)(ws + 0);          // 18.9 MB (dead after gemm_qkv)
  unsigned short* BcatT = (unsigned short*)(ws + 18874368);   // 10.6 MB (dead after gemm_qkv)
  float*          QKV   = (float*)(ws + 29491200);            // 37.7 MB (dead after split_qkv)
  unsigned short* Qcat  = (unsigned short*)(ws + 67239936);   // 18.9 MB
  unsigned short* Kcat  = (unsigned short*)(ws + 86114304);   // 18.9 MB
  unsigned short* VT    = (unsigned short*)(ws + 104988672);  //  6.3 MB
  unsigned short* Oemb  = (unsigned short*)(ws + 111280128);  //  6.3 MB
  unsigned short* WoutT = (unsigned short*)(ws + 117571584);  //  1.2 MB
  // split-K partials alias the dead Acat/BcatT/QKV region:
  float*          Opart = (float*)(ws + 0);                   // 50.3 MB
  float*          Mlpart= (float*)(ws + 50331648);            //  0.8 MB (ends 51.1 MB)

  prep_a   <<<dim3(3, 4096), 256, 0, stream>>>(x, Acat);
  prep_bqkv<<<dim3(3, 2304), 256, 0, stream>>>(Wqkv, BcatT);
  prep_wout<<<dim3(3, 768),  256, 0, stream>>>(Wout, WoutT);
  gemm_bf16_128<<<dim3(18, 32), 256, 0, stream>>>(Acat, BcatT, bqkv, QKV, 4096, 2304, 2304);
  split_qkv<<<dim3(9, 4096), 256, 0, stream>>>(QKV, Qcat, Kcat, VT);
  attn<<<dim3(32, 24, 2), 256, 0, stream>>>(Qcat, Kcat, VT, Opart, Mlpart);
  attn_combine<<<dim3(12288), 256, 0, stream>>>(Opart, Mlpart, (__bf16*)Oemb);
  gemm_bf16_128<<<dim3(6, 32), 256, 0, stream>>>(Oemb, WoutT, bout, out, 4096, 768, 768);
}

// Round 5
// 275.685 us; speedup vs baseline: 1.0486x; 1.0486x over previous
//
#include <hip/hip_runtime.h>
#include <stdint.h>

#define LOG2E 1.44269504088896340736f

typedef __bf16 v8bf __attribute__((ext_vector_type(8)));
typedef float f32x4 __attribute__((ext_vector_type(4)));
typedef float f32x16 __attribute__((ext_vector_type(16)));
typedef unsigned int v4u __attribute__((ext_vector_type(4)));
typedef unsigned int v2u __attribute__((ext_vector_type(2)));

// ---------- helpers ----------
__device__ __forceinline__ unsigned short f2bf(float f) {
  union { float f; uint32_t u; } v; v.f = f;
  uint32_t u = v.u;
  uint32_t r = (u + 0x7FFFu + ((u >> 16) & 1u)) >> 16;   // RN-even
  return (unsigned short)r;
}
__device__ __forceinline__ float bf2f(unsigned short h) {
  union { uint32_t u; float f; } v; v.u = ((uint32_t)h) << 16;
  return v.f;
}
__device__ __forceinline__ void gll16(const void* g, void* l) {
  __builtin_amdgcn_global_load_lds(
      (const __attribute__((address_space(1))) unsigned int*)g,
      (__attribute__((address_space(3))) unsigned int*)l, 16, 0, 0);
}
__device__ __forceinline__ uint32_t pk2(float a, float b) {
  union { __bf16 h[2]; uint32_t u; } x;
  x.h[0] = (__bf16)a; x.h[1] = (__bf16)b;
  return x.u;
}

// ---------- prep: x -> [hi | lo | hi]  (4096 x 2304 bf16) ----------
__global__ void prep_a(const float* __restrict__ x, unsigned short* __restrict__ Acat) {
  int n = blockIdx.x * 256 + threadIdx.x;   // 0..767
  int m = blockIdx.y;                       // 0..4095
  float v = x[(size_t)m * 768 + n];
  unsigned short H = f2bf(v);
  unsigned short L = f2bf(v - bf2f(H));
  size_t base = (size_t)m * 2304;
  Acat[base + n] = H;
  Acat[base + 768 + n] = L;
  Acat[base + 1536 + n] = H;
}

// ---------- prep: Wqkv^T cat -> rows n: [Whi | Whi | Wlo] (2304 x 2304 bf16) ----------
__global__ void prep_bqkv(const float* __restrict__ W, unsigned short* __restrict__ BT) {
  int k = blockIdx.x * 256 + threadIdx.x;   // 0..767
  int n = blockIdx.y;                       // 0..2303
  float v = W[(size_t)k * 2304 + n];
  unsigned short H = f2bf(v);
  unsigned short L = f2bf(v - bf2f(H));
  size_t base = (size_t)n * 2304;
  BT[base + k] = H;
  BT[base + 768 + k] = H;
  BT[base + 1536 + k] = L;
}

// ---------- prep: Wout^T single bf16 (768 x 768) ----------
__global__ void prep_wout(const float* __restrict__ W, unsigned short* __restrict__ BT) {
  int k = blockIdx.x * 256 + threadIdx.x;   // 0..767
  int n = blockIdx.y;                       // 0..767
  BT[(size_t)n * 768 + k] = f2bf(W[(size_t)k * 768 + n]);
}

// ---------- GEMM: C[M,N] = A[M,K](bf16) * B^T[N,K](bf16) + bias[N], fp32 out ----------
__global__ __launch_bounds__(256) void gemm_bf16_128(
    const unsigned short* __restrict__ A, const unsigned short* __restrict__ B,
    const float* __restrict__ bias, float* __restrict__ C,
    int M, int N, int K) {
  __shared__ unsigned short As[128 * 32];
  __shared__ unsigned short Bs[128 * 32];
  const int t = threadIdx.x;
  const int m0 = blockIdx.y * 128, n0 = blockIdx.x * 128;
  const int w = t >> 6, l = t & 63;
  const int wm = (w >> 1) * 64, wn = (w & 1) * 64;
  const int lr = l & 15, lg = l >> 4;
  f32x4 acc[4][4] = {};
  const int nk = K >> 5;
  for (int kt = 0; kt < nk; ++kt) {
    const int k0 = kt << 5;
    {
      const int c0 = t, c1 = t + 256;
      gll16(A + (size_t)(m0 + (c0 >> 2)) * K + k0 + ((c0 & 3) << 3), &As[c0 * 8]);
      gll16(A + (size_t)(m0 + (c1 >> 2)) * K + k0 + ((c1 & 3) << 3), &As[c1 * 8]);
      gll16(B + (size_t)(n0 + (c0 >> 2)) * K + k0 + ((c0 & 3) << 3), &Bs[c0 * 8]);
      gll16(B + (size_t)(n0 + (c1 >> 2)) * K + k0 + ((c1 & 3) << 3), &Bs[c1 * 8]);
    }
    __syncthreads();
    v8bf a[4], b[4];
#pragma unroll
    for (int i = 0; i < 4; i++) {
      a[i] = *(const v8bf*)&As[(wm + i * 16 + lr) * 32 + lg * 8];
      b[i] = *(const v8bf*)&Bs[(wn + i * 16 + lr) * 32 + lg * 8];
    }
#pragma unroll
    for (int i = 0; i < 4; i++)
#pragma unroll
      for (int j = 0; j < 4; j++)
        acc[i][j] = __builtin_amdgcn_mfma_f32_16x16x32_bf16(a[i], b[j], acc[i][j], 0, 0, 0);
    __syncthreads();
  }
#pragma unroll
  for (int i = 0; i < 4; i++) {
#pragma unroll
    for (int j = 0; j < 4; j++) {
      const int col = n0 + wn + j * 16 + lr;
      const float bv = bias[col];
#pragma unroll
      for (int r = 0; r < 4; r++) {
        const int row = m0 + wm + i * 16 + lg * 4 + r;
        C[(size_t)row * N + col] = acc[i][j][r] + bv;
      }
    }
  }
}

// ---------- split qkv fp32 -> Qcat/Kcat (split-bf16, *8 folded into Q), V^T bf16 ----------
__global__ void split_qkv(const float* __restrict__ qkv,
                          unsigned short* __restrict__ Qc,
                          unsigned short* __restrict__ Kc,
                          unsigned short* __restrict__ VT) {
  int n = blockIdx.x * 256 + threadIdx.x;   // 0..2303
  int m = blockIdx.y;                       // 0..4095
  float val = qkv[(size_t)m * 2304 + n];
  int h = n / 192;
  int j = n - h * 192;
  int b = m >> 11, p = m & 2047;
  int bh = b * 12 + h;
  size_t base = (size_t)bh * 2048 * 192 + (size_t)p * 192;
  if (j < 64) {
    float v8v = val * 8.0f;                 // fold logits *= sqrt(64) (exact: pow2)
    unsigned short H = f2bf(v8v);
    unsigned short L = f2bf(v8v - bf2f(H));
    Qc[base + j] = H; Qc[base + 64 + j] = L; Qc[base + 128 + j] = H;
  } else if (j < 128) {
    int d = j - 64;
    unsigned short H = f2bf(val);
    unsigned short L = f2bf(val - bf2f(H));
    Kc[base + d] = H; Kc[base + 64 + d] = H; Kc[base + 128 + d] = L;
  } else {
    int d = j - 128;
    VT[(size_t)bh * 64 * 2048 + (size_t)d * 2048 + p] = f2bf(val);
  }
}

// ---------- flash attention: 32x32 swapped-QK^T, in-register softmax ----------
// grid (16 q-tiles, 24 bh, 2 key-splits), 256 threads = 4 waves, QBLK=32/wave.
// s = mfma(A=K, B=Q): lane owns q-col (l&31); its 16 C-regs/frag hold keys
// (r&3)+8*(r>>2)+4*(l>>5) -> softmax is lane-local + ONE permlane32_swap.
// P -> PV A-frags fully in-register via cvt_pk + permlane32_swap (T12).
// K/V reg-staged (T14), LDS XOR-swizzled (^(row&7)<<3 on elem idx). No Ps LDS.
__global__ __launch_bounds__(256) void attn(
    const unsigned short* __restrict__ Qc, const unsigned short* __restrict__ Kc,
    const unsigned short* __restrict__ VT,
    float* __restrict__ Op, float* __restrict__ Ml) {
  __shared__ __align__(16) unsigned short Ks[64 * 192];
  __shared__ __align__(16) unsigned short Vs[64 * 64];
  __shared__ float Al[4][32];
  const int t = threadIdx.x, w = t >> 6, l = t & 63;
  const int lq = l & 31, hi = l >> 5;
  const int bh = blockIdx.y, q0 = blockIdx.x * 128;
  const int qw0 = q0 + w * 32;
  const int ktBase = blockIdx.z * 16;           // 16 K-tiles per split
  const unsigned short* Qb = Qc + (size_t)bh * 2048 * 192;
  const unsigned short* Kb = Kc + (size_t)bh * 2048 * 192;
  const unsigned short* Vb = VT + (size_t)bh * 64 * 2048;

  // hoisted swizzled LDS write offsets (element units)
  int kwofs[6];
#pragma unroll
  for (int i = 0; i < 6; i++) {
    int c = t + i * 256;                    // 16B chunk id; 24 chunks per 192-elem row
    int row = c / 24, cc = c - row * 24;
    kwofs[i] = (row * 192 + cc * 8) ^ ((row & 7) << 3);
  }
  int vwofs[2];
#pragma unroll
  for (int i = 0; i < 2; i++) {
    int c = t + i * 256;                    // 8 chunks per 64-elem V^T row
    int d = c >> 3, part = c & 7;
    vwofs[i] = (d * 64 + part * 8) ^ ((d & 7) << 3);
  }
  // linear global source pointers (coalesced), bumped per kt
  const char* gK = (const char*)Kb + (size_t)ktBase * 24576 + (size_t)t * 16;
  const char* gV = (const char*)Vb + (size_t)(t >> 3) * 4096 + (size_t)(t & 7) * 16
                   + (size_t)ktBase * 128;

  v4u kreg[6], vreg[2];
#pragma unroll
  for (int i = 0; i < 6; i++) kreg[i] = *(const v4u*)(gK + i * 4096);
#pragma unroll
  for (int i = 0; i < 2; i++) vreg[i] = *(const v4u*)(gV + i * 131072);

  // Q B-frags, resident: lane holds Q[qw0+lq][ks*16 + hi*8 .. +7]
  v8bf qf[12];
#pragma unroll
  for (int ks = 0; ks < 12; ++ks)
    qf[ks] = *(const v8bf*)(Qb + (size_t)(qw0 + lq) * 192 + ks * 16 + hi * 8);

  f32x16 o0 = {}, o1 = {};
  float mrun = -1e30f, lsum = 0.f;
  const int sx = (l & 7) << 3;              // read swizzle: rows are lq / lq+32 / d

  for (int kt = 0; kt < 16; ++kt) {
    // drain staged regs to LDS
#pragma unroll
    for (int i = 0; i < 6; i++) *(v4u*)&Ks[kwofs[i]] = kreg[i];
#pragma unroll
    for (int i = 0; i < 2; i++) *(v4u*)&Vs[vwofs[i]] = vreg[i];
    __syncthreads();

    // issue next tile's loads — fly during this tile's compute
    if (kt < 15) {
      gK += 24576; gV += 128;
#pragma unroll
      for (int i = 0; i < 6; i++) kreg[i] = *(const v4u*)(gK + i * 4096);
#pragma unroll
      for (int i = 0; i < 2; i++) vreg[i] = *(const v4u*)(gV + i * 131072);
    }

    // S^T = K Q^T : s0 = keys 0-31, s1 = keys 32-63 (cols = q)
    f32x16 s0 = {}, s1 = {};
    __builtin_amdgcn_s_setprio(1);
#pragma unroll
    for (int ks = 0; ks < 12; ++ks) {
      v8bf ka = *(const v8bf*)&Ks[((lq) * 192 + ks * 16 + hi * 8) ^ sx];
      v8bf kb = *(const v8bf*)&Ks[((lq + 32) * 192 + ks * 16 + hi * 8) ^ sx];
      s0 = __builtin_amdgcn_mfma_f32_32x32x16_bf16(ka, qf[ks], s0, 0, 0, 0);
      s1 = __builtin_amdgcn_mfma_f32_32x32x16_bf16(kb, qf[ks], s1, 0, 0, 0);
    }
    __builtin_amdgcn_s_setprio(0);

    // ---- lane-local softmax over 32 values + one half-swap ----
    float tm[16];
#pragma unroll
    for (int i = 0; i < 16; i++) tm[i] = fmaxf(s0[i], s1[i]);
#pragma unroll
    for (int i = 0; i < 8; i++) tm[i] = fmaxf(tm[i], tm[i + 8]);
#pragma unroll
    for (int i = 0; i < 4; i++) tm[i] = fmaxf(tm[i], tm[i + 4]);
    float pmax = fmaxf(fmaxf(tm[0], tm[1]), fmaxf(tm[2], tm[3]));
    {
      v2u r = __builtin_amdgcn_permlane32_swap(__float_as_uint(pmax),
                                               __float_as_uint(pmax), false, false);
      pmax = fmaxf(__uint_as_float(r.x), __uint_as_float(r.y));
    }

    // T13 defer-max (THR=8)
    if (__any(pmax > mrun + 8.f)) {
      float mnew = fmaxf(mrun, pmax);
      float a = __builtin_exp2f((mrun - mnew) * LOG2E);
      mrun = mnew;
      lsum *= a;
      if (!hi) Al[w][lq] = a;
      asm volatile("s_waitcnt lgkmcnt(0)" ::: "memory");
#pragma unroll
      for (int r = 0; r < 16; r++) {
        float ar = Al[w][(r & 3) + 8 * (r >> 2) + 4 * hi];
        o0[r] *= ar; o1[r] *= ar;
      }
    }

    // P = exp(S - m), accumulate row-sum, build PV A-frags in-register
    const float mL = mrun * LOG2E;
    float p[16];
    float ps = 0.f;
    uint32_t paw[4][4];                      // [ks][word]
    // s0 -> keys 0-31 -> PV ks=0,1
#pragma unroll
    for (int i = 0; i < 16; i++) { p[i] = __builtin_exp2f(s0[i] * LOG2E - mL); ps += p[i]; }
    {
      v2u r0 = __builtin_amdgcn_permlane32_swap(pk2(p[0], p[1]), pk2(p[4], p[5]), false, false);
      v2u r1 = __builtin_amdgcn_permlane32_swap(pk2(p[2], p[3]), pk2(p[6], p[7]), false, false);
      paw[0][0] = r0.x; paw[0][2] = r0.y; paw[0][1] = r1.x; paw[0][3] = r1.y;
      v2u r2 = __builtin_amdgcn_permlane32_swap(pk2(p[8], p[9]), pk2(p[12], p[13]), false, false);
      v2u r3 = __builtin_amdgcn_permlane32_swap(pk2(p[10], p[11]), pk2(p[14], p[15]), false, false);
      paw[1][0] = r2.x; paw[1][2] = r2.y; paw[1][1] = r3.x; paw[1][3] = r3.y;
    }
    // s1 -> keys 32-63 -> PV ks=2,3
#pragma unroll
    for (int i = 0; i < 16; i++) { p[i] = __builtin_exp2f(s1[i] * LOG2E - mL); ps += p[i]; }
    {
      v2u r0 = __builtin_amdgcn_permlane32_swap(pk2(p[0], p[1]), pk2(p[4], p[5]), false, false);
      v2u r1 = __builtin_amdgcn_permlane32_swap(pk2(p[2], p[3]), pk2(p[6], p[7]), false, false);
      paw[2][0] = r0.x; paw[2][2] = r0.y; paw[2][1] = r1.x; paw[2][3] = r1.y;
      v2u r2 = __builtin_amdgcn_permlane32_swap(pk2(p[8], p[9]), pk2(p[12], p[13]), false, false);
      v2u r3 = __builtin_amdgcn_permlane32_swap(pk2(p[10], p[11]), pk2(p[14], p[15]), false, false);
      paw[3][0] = r2.x; paw[3][2] = r2.y; paw[3][1] = r3.x; paw[3][3] = r3.y;
    }
    {
      v2u r = __builtin_amdgcn_permlane32_swap(__float_as_uint(ps),
                                               __float_as_uint(ps), false, false);
      lsum += __uint_as_float(r.x) + __uint_as_float(r.y);
    }

    // O += P V  (B-frags from Vs rows = d, contiguous along keys)
    __builtin_amdgcn_s_setprio(1);
#pragma unroll
    for (int ks = 0; ks < 4; ++ks) {
      union { uint32_t u[4]; v8bf v; } pa;
      pa.u[0] = paw[ks][0]; pa.u[1] = paw[ks][1];
      pa.u[2] = paw[ks][2]; pa.u[3] = paw[ks][3];
      v8bf v0 = *(const v8bf*)&Vs[((lq) * 64 + ks * 16 + hi * 8) ^ sx];
      v8bf v1 = *(const v8bf*)&Vs[((lq + 32) * 64 + ks * 16 + hi * 8) ^ sx];
      o0 = __builtin_amdgcn_mfma_f32_32x32x16_bf16(pa.v, v0, o0, 0, 0, 0);
      o1 = __builtin_amdgcn_mfma_f32_32x32x16_bf16(pa.v, v1, o1, 0, 0, 0);
    }
    __builtin_amdgcn_s_setprio(0);
    __syncthreads();
  }

  // epilogue: partial (unnormalized) O + (m,l) per q-row
  const size_t S = (size_t)24 * 2048;
  const size_t srow = (size_t)blockIdx.z * S + (size_t)bh * 2048;
  if (!hi) {
    Ml[(srow + qw0 + lq) * 2]     = mrun;
    Ml[(srow + qw0 + lq) * 2 + 1] = lsum;
  }
#pragma unroll
  for (int r = 0; r < 16; r++) {
    const int q = qw0 + (r & 3) + 8 * (r >> 2) + 4 * hi;
    Op[(srow + q) * 64 + lq]      = o0[r];
    Op[(srow + q) * 64 + 32 + lq] = o1[r];
  }
}

// ---------- combine the two split-K partials ----------
__global__ __launch_bounds__(256) void attn_combine(
    const float* __restrict__ Op, const float* __restrict__ Ml,
    __bf16* __restrict__ Oe) {
  const size_t S = (size_t)24 * 2048;
  int row = blockIdx.x * 4 + (threadIdx.x >> 6);   // bh*2048 + q, 0..49151
  int lane = threadIdx.x & 63;
  int bh = row >> 11, q = row & 2047;
  int b = bh / 12, h = bh - b * 12;
  float m1 = Ml[(size_t)row * 2], l1 = Ml[(size_t)row * 2 + 1];
  float m2 = Ml[(S + row) * 2],   l2 = Ml[(S + row) * 2 + 1];
  float M = fmaxf(m1, m2);
  float a1 = __builtin_exp2f((m1 - M) * LOG2E);
  float a2 = __builtin_exp2f((m2 - M) * LOG2E);
  float rinv = 1.0f / (l1 * a1 + l2 * a2);
  float o1 = Op[(size_t)row * 64 + lane];
  float o2 = Op[S * 64 + (size_t)row * 64 + lane];
  Oe[((size_t)(b * 2048 + q)) * 768 + h * 64 + lane] = (__bf16)((o1 * a1 + o2 * a2) * rinv);
}

// ---------- launcher ----------
extern "C" void kernel_launch(void* const* d_in, const int* in_sizes, int n_in,
                              void* d_out, int out_size, void* d_ws, size_t ws_size,
                              hipStream_t stream) {
  const float* x    = (const float*)d_in[0];
  const float* Wqkv = (const float*)d_in[1];
  const float* bqkv = (const float*)d_in[2];
  const float* Wout = (const float*)d_in[3];
  const float* bout = (const float*)d_in[4];
  float* out = (float*)d_out;
  char* ws = (char*)d_ws;

  unsigned short* Acat  = (unsigned short*)(ws + 0);          // 18.9 MB (dead after gemm_qkv)
  unsigned short* BcatT = (unsigned short*)(ws + 18874368);   // 10.6 MB (dead after gemm_qkv)
  float*          QKV   = (float*)(ws + 29491200);            // 37.7 MB (dead after split_qkv)
  unsigned short* Qcat  = (unsigned short*)(ws + 67239936);   // 18.9 MB
  unsigned short* Kcat  = (unsigned short*)(ws + 86114304);   // 18.9 MB
  unsigned short* VT    = (unsigned short*)(ws + 104988672);  //  6.3 MB
  unsigned short* Oemb  = (unsigned short*)(ws + 111280128);  //  6.3 MB
  unsigned short* WoutT = (unsigned short*)(ws + 117571584);  //  1.2 MB
  // split-K partials alias the dead Acat/BcatT/QKV region:
  float*          Opart = (float*)(ws + 0);                   // 50.3 MB
  float*          Mlpart= (float*)(ws + 50331648);            //  0.8 MB (ends 51.1 MB)

  prep_a   <<<dim3(3, 4096), 256, 0, stream>>>(x, Acat);
  prep_bqkv<<<dim3(3, 2304), 256, 0, stream>>>(Wqkv, BcatT);
  prep_wout<<<dim3(3, 768),  256, 0, stream>>>(Wout, WoutT);
  gemm_bf16_128<<<dim3(18, 32), 256, 0, stream>>>(Acat, BcatT, bqkv, QKV, 4096, 2304, 2304);
  split_qkv<<<dim3(9, 4096), 256, 0, stream>>>(QKV, Qcat, Kcat, VT);
  attn<<<dim3(16, 24, 2), 256, 0, stream>>>(Qcat, Kcat, VT, Opart, Mlpart);
  attn_combine<<<dim3(12288), 256, 0, stream>>>(Opart, Mlpart, (__bf16*)Oemb);
  gemm_bf16_128<<<dim3(6, 32), 256, 0, stream>>>(Oemb, WoutT, bout, out, 4096, 768, 768);
}